// Round 4
// baseline (653.014 us; speedup 1.0000x reference)
//
#include <hip/hip_runtime.h>
#include <hip/hip_bf16.h>

// StyleLayer: modulated conv3x3 as bf16 MFMA implicit GEMM (demod folded into
// input/output scales) + fused polyphase upfirdn(up2)->lrelu/clamp->upfirdn(down2).
// B=8, CIN=COUT=SDIM=512, H=W=64, K=3, taps=12, out 64x64. Conv out 66x66 (=4356 px).

#define B_    8
#define CIN_  512
#define COUT_ 512
#define SDIM_ 512
#define H_    64
#define W_    64
#define HO_   66
#define NPIX  4356          // 66*66
#define XP    68            // padded input spatial (origin shift 2)

typedef short s8v  __attribute__((ext_vector_type(8)));   // 8 bf16 in 4 VGPRs
typedef float f4v  __attribute__((ext_vector_type(4)));

// ---------------- s[b,c] = w @ (aw/sqrt(SDIM)).T + ab ----------------
__global__ void k_style_s(const float* __restrict__ w, const float* __restrict__ aw,
                          const float* __restrict__ ab, float* __restrict__ s) {
    int t = blockIdx.x * blockDim.x + threadIdx.x;    // 4096 = b*512+c
    int b = t >> 9, c = t & 511;
    const float inv = 0.044194173824159216f;          // 1/sqrt(512)
    const float* wp = w + b * SDIM_;
    const float* ap = aw + c * SDIM_;
    float acc = 0.f;
    for (int k = 0; k < SDIM_; ++k) acc += wp[k] * ap[k];
    s[t] = acc * inv + ab[c];
}

// ---------------- r[o,c] = sum_k cw[o,c,k]^2 ----------------
__global__ void k_style_r(const float* __restrict__ cw, float* __restrict__ r) {
    int t = blockIdx.x * blockDim.x + threadIdx.x;    // 262144 = o*512+c
    const float* p = cw + t * 9;
    float a = 0.f;
    #pragma unroll
    for (int k = 0; k < 9; ++k) a += p[k] * p[k];
    r[t] = a;
}

// ---------------- coef[b,o] = scale * d[b,o] * rsqrt(ema) ----------------
__global__ void k_style_coef(const float* __restrict__ s, const float* __restrict__ r,
                             const float* __restrict__ ema, float* __restrict__ coef) {
    int t = blockIdx.x * blockDim.x + threadIdx.x;    // 4096 = b*512+o
    int b = t >> 9, o = t & 511;
    const float scale2 = 1.0f / 4608.0f;
    const float* sp = s + b * 512;
    const float* rp = r + o * 512;
    float acc = 0.f;
    for (int c = 0; c < 512; ++c) { float sv = sp[c]; acc += sv * sv * rp[c]; }
    float d  = rsqrtf(scale2 * acc + 1e-8f);
    float ig = rsqrtf(ema[0]);
    coef[t] = d * ig * 0.014731391274719739f;         // * 1/sqrt(4608)
}

// ---------------- wb[tap][o][c] = bf16(cw[o][c][tap]) ----------------
__global__ __launch_bounds__(256) void k_prep_w(const float* __restrict__ cw,
                                                __hip_bfloat16* __restrict__ wb) {
    int t = blockIdx.x * 256 + threadIdx.x;           // 9*512*512 = 2359296
    int tap = t / (512 * 512);
    int rem = t - tap * 512 * 512;
    int o = rem >> 9, c = rem & 511;
    wb[t] = __float2bfloat16(cw[(o * 512 + c) * 9 + tap]);
}

// ---------------- xt[b][y][x][c] = bf16(x[b][c][y-2][x-2] * s[b][c]), zero pad ----
__global__ __launch_bounds__(256) void k_prep_x(const float* __restrict__ x,
                                                const float* __restrict__ s,
                                                __hip_bfloat16* __restrict__ xt) {
    __shared__ float tile[64][65];
    const int y = blockIdx.x;            // 0..67
    const int b = blockIdx.y;
    const int tid = threadIdx.x;
    const bool yin = (y >= 2 && y < 66);
    __hip_bfloat16* orow = xt + ((size_t)(b * XP + y)) * XP * 512;
    for (int c0 = 0; c0 < 512; c0 += 64) {
        if (yin) {
            for (int i = tid; i < 64 * 64; i += 256) {
                int c = i >> 6, xx = i & 63;
                tile[c][xx] = x[(((size_t)b * 512 + c0 + c) * 64 + (y - 2)) * 64 + xx]
                              * s[b * 512 + c0 + c];
            }
        }
        __syncthreads();
        for (int j = tid; j < 68 * 8; j += 256) {     // 68 x-positions, 8 c-groups of 8
            int xx = j >> 3, cg = j & 7;
            bool xin = yin && (xx >= 2 && xx < 66);
            union { ushort u[8]; float4 f4; } pk;
            #pragma unroll
            for (int k = 0; k < 8; ++k) {
                float v = xin ? tile[cg * 8 + k][xx - 2] : 0.f;
                __hip_bfloat16 h = __float2bfloat16(v);
                pk.u[k] = *reinterpret_cast<ushort*>(&h);
            }
            *reinterpret_cast<float4*>(orow + (size_t)xx * 512 + c0 + cg * 8) = pk.f4;
        }
        __syncthreads();
    }
}

// ---------------- MFMA implicit-GEMM conv ----------------
// 128 o x 128 px tile, K = 9 taps x 512 c, BK=32, 2-phase double buffer.
// All per-lane addresses hoisted; per-step offset is wave-uniform SALU only.
__device__ __forceinline__ void gload16(const void* g, void* l) {
    __builtin_amdgcn_global_load_lds(
        (const __attribute__((address_space(1))) unsigned*)g,
        (__attribute__((address_space(3))) unsigned*)l, 16, 0, 0);
}

__global__ __launch_bounds__(256) void k_conv_mfma(
    const __hip_bfloat16* __restrict__ wb, const __hip_bfloat16* __restrict__ xt,
    const float* __restrict__ coef, const float* __restrict__ bias,
    __hip_bfloat16* __restrict__ y1)
{
    __shared__ __hip_bfloat16 lds[2][2][128][32];     // [buf][A|B][row][c]

    // bijective XCD swizzle (1120 % 8 == 0): each XCD gets 140 consecutive
    // flat ids; o-major order keeps one 1.18 MB wb panel L2-resident per chunk.
    int flat = blockIdx.x + 35 * (blockIdx.y + 4 * blockIdx.z);
    { int xcd = flat & 7, idx = flat >> 3; flat = xcd * 140 + idx; }
    const int pi = flat % 35;
    const int t2 = flat / 35;                         // 0..31: (oi*8 + b)
    const int b  = t2 & 7;
    const int o0 = (t2 >> 3) * 128;
    const int p0 = pi * 128;

    const int tid = threadIdx.x, wv = tid >> 6, ln = tid & 63;
    const int wm = wv >> 1, wn = wv & 1;

    // ---- per-lane staging base addresses (loop-invariant) ----
    const char* baseA[2];
    const char* baseB[2];
    #pragma unroll
    for (int i = 0; i < 2; ++i) {
        int j = i * 256 + wv * 64 + ln;
        int row = j >> 2, sl = j & 3;
        baseA[i] = (const char*)(wb + (size_t)(o0 + row) * 512
                                 + ((sl ^ ((row >> 1) & 3)) << 3));
        int p = p0 + row; if (p > NPIX - 1) p = NPIX - 1;
        int py = (int)(((unsigned)p * 63551u) >> 22); // p/66
        int px = p - py * 66;
        baseB[i] = (const char*)(xt + (size_t)b * XP * XP * 512
                                 + (size_t)(py * XP + px) * 512
                                 + ((sl ^ ((row >> 1) & 3)) << 3));
    }

    // ---- per-lane LDS fragment element offsets (loop-invariant) ----
    int aoff[4], boff[4];
    #pragma unroll
    for (int f = 0; f < 4; ++f) {
        int r  = wm * 64 + f * 16 + (ln & 15);
        aoff[f] = r * 32 + (((ln >> 4) ^ ((r >> 1) & 3)) << 3);
        int rb = wn * 64 + f * 16 + (ln & 15);
        boff[f] = rb * 32 + (((ln >> 4) ^ ((rb >> 1) & 3)) << 3);
    }

    f4v acc[4][4];
    #pragma unroll
    for (int fm = 0; fm < 4; ++fm)
        #pragma unroll
        for (int fn = 0; fn < 4; ++fn) acc[fm][fn] = (f4v){0.f, 0.f, 0.f, 0.f};

    auto stage = [&](int st, int buf) {
        int tap = st >> 4;                            // uniform -> SALU
        int ki  = (tap * 11) >> 5;                    // tap/3 for tap<9
        int kj  = tap - ki * 3;
        unsigned ccb  = (unsigned)(st & 15) << 6;     // c-chunk bytes
        unsigned offA = (unsigned)tap * 524288u + ccb;            // tap*512*512*2B
        unsigned offB = (unsigned)(ki * XP + kj) * 1024u + ccb;   // (ki*XP+kj)*512*2B
        __hip_bfloat16* dA = &lds[buf][0][0][0] + (size_t)wv * 512;
        __hip_bfloat16* dB = &lds[buf][1][0][0] + (size_t)wv * 512;
        #pragma unroll
        for (int i = 0; i < 2; ++i) {
            gload16(baseA[i] + offA, dA + i * 2048);
            gload16(baseB[i] + offB, dB + i * 2048);
        }
    };

    stage(0, 0);
    __syncthreads();

    for (int st = 0; st < 144; ++st) {
        const int cur = st & 1;
        if (st != 143) stage(st + 1, cur ^ 1);
        const __hip_bfloat16* A  = &lds[cur][0][0][0];
        const __hip_bfloat16* Bm = &lds[cur][1][0][0];
        s8v af[4], bfv[4];
        #pragma unroll
        for (int f = 0; f < 4; ++f) {
            af[f]  = *reinterpret_cast<const s8v*>(A  + aoff[f]);
            bfv[f] = *reinterpret_cast<const s8v*>(Bm + boff[f]);
        }
        #pragma unroll
        for (int fm = 0; fm < 4; ++fm)
            #pragma unroll
            for (int fn = 0; fn < 4; ++fn)
                acc[fm][fn] = __builtin_amdgcn_mfma_f32_16x16x32_bf16(
                    af[fm], bfv[fn], acc[fm][fn], 0, 0, 0);
        __syncthreads();
    }

    // epilogue: y1[b][o][p] bf16 = acc*coef + bias
    #pragma unroll
    for (int fm = 0; fm < 4; ++fm) {
        #pragma unroll
        for (int fn = 0; fn < 4; ++fn) {
            int p = p0 + wn * 64 + fn * 16 + (ln & 15);
            if (p < NPIX) {
                int ob = o0 + wm * 64 + fm * 16 + (ln >> 4) * 4;
                #pragma unroll
                for (int j = 0; j < 4; ++j) {
                    int o = ob + j;
                    float v = acc[fm][fn][j] * coef[b * 512 + o] + bias[o];
                    y1[((size_t)(b * 512 + o)) * NPIX + p] = __float2bfloat16(v);
                }
            }
        }
    }
}

// ---------------- fused upfirdn2(up2,pad(9,8)) -> lrelu*sqrt2,clamp -> upfirdn2(down2) ----
// 32x32 output tile per block (was 16x16): 1/4 the blocks, read-amp 2.64 -> 1.72.
__global__ __launch_bounds__(256) void k_style_fir(
    const __hip_bfloat16* __restrict__ y1, const float* __restrict__ uf,
    const float* __restrict__ df, float* __restrict__ out)
{
    __shared__ float It[42][43];
    __shared__ float hu[42][75];
    __shared__ float zt[74][75];
    __shared__ float dh[74][33];
    const int img = blockIdx.z;          // b*COUT + o
    const int oy0 = blockIdx.y * 32;
    const int ox0 = blockIdx.x * 32;
    const int tid = threadIdx.x;
    const __hip_bfloat16* I = y1 + (size_t)img * NPIX;

    for (int i = tid; i < 42 * 42; i += 256) {
        int rr = i / 42, cc = i % 42;
        int gy = oy0 - 4 + rr, gx = ox0 - 4 + cc;
        float v = 0.f;
        if (gy >= 0 && gy < HO_ && gx >= 0 && gx < HO_) v = __bfloat162float(I[gy * HO_ + gx]);
        It[rr][cc] = v;
    }
    __syncthreads();

    for (int i = tid; i < 42 * 74; i += 256) {
        int m = i / 74, rr = i % 74;
        float a = 0.f;
        if ((rr & 1) == 0) {
            int base = rr / 2 + 5;
            #pragma unroll
            for (int q = 0; q < 6; ++q) a += uf[2 * q] * It[m][base - q];
        } else {
            int base = (rr + 1) / 2 + 4;
            #pragma unroll
            for (int q = 0; q < 6; ++q) a += uf[2 * q + 1] * It[m][base - q];
        }
        hu[m][rr] = 2.f * a;
    }
    __syncthreads();

    for (int i = tid; i < 74 * 74; i += 256) {
        int ry = i / 74, rx = i % 74;
        float a = 0.f;
        if ((ry & 1) == 0) {
            int base = ry / 2 + 5;
            #pragma unroll
            for (int q = 0; q < 6; ++q) a += uf[2 * q] * hu[base - q][rx];
        } else {
            int base = (ry + 1) / 2 + 4;
            #pragma unroll
            for (int q = 0; q < 6; ++q) a += uf[2 * q + 1] * hu[base - q][rx];
        }
        a *= 2.f;
        a = (a >= 0.f ? a : a * 0.2f) * 1.4142135623730951f;
        a = fminf(fmaxf(a, -256.f), 256.f);
        zt[ry][rx] = a;
    }
    __syncthreads();

    for (int i = tid; i < 74 * 32; i += 256) {
        int ry = i / 32, oxl = i % 32;
        float a = 0.f;
        #pragma unroll
        for (int u = 0; u < 12; ++u) a += zt[ry][2 * oxl + u] * df[11 - u];
        dh[ry][oxl] = a;
    }
    __syncthreads();

    for (int i = tid; i < 32 * 32; i += 256) {
        int oyl = i / 32, oxl = i % 32;
        float a = 0.f;
        #pragma unroll
        for (int v = 0; v < 12; ++v) a += dh[2 * oyl + v][oxl] * df[11 - v];
        out[(size_t)img * 64 * 64 + (oy0 + oyl) * 64 + (ox0 + oxl)] = a;
    }
}

extern "C" void kernel_launch(void* const* d_in, const int* in_sizes, int n_in,
                              void* d_out, int out_size, void* d_ws, size_t ws_size,
                              hipStream_t stream) {
    const float* x    = (const float*)d_in[0];
    const float* w    = (const float*)d_in[1];
    const float* aw   = (const float*)d_in[2];
    const float* ab   = (const float*)d_in[3];
    const float* cw   = (const float*)d_in[4];
    const float* bias = (const float*)d_in[5];
    const float* uf   = (const float*)d_in[6];
    const float* df   = (const float*)d_in[7];
    const float* ema  = (const float*)d_in[8];
    float* out = (float*)d_out;

    float* ws   = (float*)d_ws;
    float* s_   = ws;                                   // 4096
    float* coef = ws + 4096;                            // 4096
    float* r_   = ws + 8192;                            // 262144
    // bf16 regions (sizes in float-slots): y1 8,921,088 | xt 9,469,952 | wb 1,179,648
    __hip_bfloat16* y1 = (__hip_bfloat16*)(ws + 270336);
    __hip_bfloat16* xt = (__hip_bfloat16*)(ws + 270336 + 8921088);
    __hip_bfloat16* wb = (__hip_bfloat16*)(ws + 270336 + 8921088 + 9469952);

    k_style_s   <<<16,   256, 0, stream>>>(w, aw, ab, s_);
    k_style_r   <<<1024, 256, 0, stream>>>(cw, r_);
    k_style_coef<<<16,   256, 0, stream>>>(s_, r_, ema, coef);
    k_prep_w    <<<9216, 256, 0, stream>>>(cw, wb);
    k_prep_x    <<<dim3(68, 8), 256, 0, stream>>>(x, s_, xt);
    k_conv_mfma <<<dim3(35, 4, 8), 256, 0, stream>>>(wb, xt, coef, bias, y1);
    k_style_fir <<<dim3(2, 2, 4096), 256, 0, stream>>>(y1, uf, df, out);
}

// Round 6
// 476.140 us; speedup vs baseline: 1.3715x; 1.3715x over previous
//
#include <hip/hip_runtime.h>
#include <hip/hip_bf16.h>

// StyleLayer: modulated conv3x3 as bf16 MFMA implicit GEMM (demod folded into
// input/output scales) + fused polyphase upfirdn(up2)->lrelu/clamp->upfirdn(down2).
// B=8, CIN=COUT=SDIM=512, H=W=64, K=3, taps=12, out 64x64. Conv out 66x66 (=4356 px).

#define B_    8
#define CIN_  512
#define COUT_ 512
#define SDIM_ 512
#define H_    64
#define W_    64
#define HO_   66
#define NPIX  4356          // 66*66
#define XP    68            // padded input spatial (origin shift 2)

typedef short s8v  __attribute__((ext_vector_type(8)));   // 8 bf16 in 4 VGPRs
typedef float f4v  __attribute__((ext_vector_type(4)));

// ---------------- s[b,c] = w @ (aw/sqrt(SDIM)).T + ab ----------------
__global__ void k_style_s(const float* __restrict__ w, const float* __restrict__ aw,
                          const float* __restrict__ ab, float* __restrict__ s) {
    int t = blockIdx.x * blockDim.x + threadIdx.x;    // 4096 = b*512+c
    int b = t >> 9, c = t & 511;
    const float inv = 0.044194173824159216f;          // 1/sqrt(512)
    const float* wp = w + b * SDIM_;
    const float* ap = aw + c * SDIM_;
    float acc = 0.f;
    for (int k = 0; k < SDIM_; ++k) acc += wp[k] * ap[k];
    s[t] = acc * inv + ab[c];
}

// ---------------- r[o,c] = sum_k cw[o,c,k]^2 ----------------
__global__ void k_style_r(const float* __restrict__ cw, float* __restrict__ r) {
    int t = blockIdx.x * blockDim.x + threadIdx.x;    // 262144 = o*512+c
    const float* p = cw + t * 9;
    float a = 0.f;
    #pragma unroll
    for (int k = 0; k < 9; ++k) a += p[k] * p[k];
    r[t] = a;
}

// ---------------- coef[b,o] = scale * d[b,o] * rsqrt(ema) ----------------
__global__ void k_style_coef(const float* __restrict__ s, const float* __restrict__ r,
                             const float* __restrict__ ema, float* __restrict__ coef) {
    int t = blockIdx.x * blockDim.x + threadIdx.x;    // 4096 = b*512+o
    int b = t >> 9, o = t & 511;
    const float scale2 = 1.0f / 4608.0f;
    const float* sp = s + b * 512;
    const float* rp = r + o * 512;
    float acc = 0.f;
    for (int c = 0; c < 512; ++c) { float sv = sp[c]; acc += sv * sv * rp[c]; }
    float d  = rsqrtf(scale2 * acc + 1e-8f);
    float ig = rsqrtf(ema[0]);
    coef[t] = d * ig * 0.014731391274719739f;         // * 1/sqrt(4608)
}

// ---------------- wb[tap][o][c] = bf16(cw[o][c][tap]) ----------------
__global__ __launch_bounds__(256) void k_prep_w(const float* __restrict__ cw,
                                                __hip_bfloat16* __restrict__ wb) {
    int t = blockIdx.x * 256 + threadIdx.x;           // 9*512*512 = 2359296
    int tap = t / (512 * 512);
    int rem = t - tap * 512 * 512;
    int o = rem >> 9, c = rem & 511;
    wb[t] = __float2bfloat16(cw[(o * 512 + c) * 9 + tap]);
}

// ---------------- xt[b][y][x][c] = bf16(x[b][c][y-2][x-2] * s[b][c]), zero pad ----
__global__ __launch_bounds__(256) void k_prep_x(const float* __restrict__ x,
                                                const float* __restrict__ s,
                                                __hip_bfloat16* __restrict__ xt) {
    __shared__ float tile[64][65];
    const int y = blockIdx.x;            // 0..67
    const int b = blockIdx.y;
    const int tid = threadIdx.x;
    const bool yin = (y >= 2 && y < 66);
    __hip_bfloat16* orow = xt + ((size_t)(b * XP + y)) * XP * 512;
    for (int c0 = 0; c0 < 512; c0 += 64) {
        if (yin) {
            for (int i = tid; i < 64 * 64; i += 256) {
                int c = i >> 6, xx = i & 63;
                tile[c][xx] = x[(((size_t)b * 512 + c0 + c) * 64 + (y - 2)) * 64 + xx]
                              * s[b * 512 + c0 + c];
            }
        }
        __syncthreads();
        for (int j = tid; j < 68 * 8; j += 256) {     // 68 x-positions, 8 c-groups of 8
            int xx = j >> 3, cg = j & 7;
            bool xin = yin && (xx >= 2 && xx < 66);
            union { ushort u[8]; float4 f4; } pk;
            #pragma unroll
            for (int k = 0; k < 8; ++k) {
                float v = xin ? tile[cg * 8 + k][xx - 2] : 0.f;
                __hip_bfloat16 h = __float2bfloat16(v);
                pk.u[k] = *reinterpret_cast<ushort*>(&h);
            }
            *reinterpret_cast<float4*>(orow + (size_t)xx * 512 + c0 + cg * 8) = pk.f4;
        }
        __syncthreads();
    }
}

// ---------------- MFMA implicit-GEMM conv ----------------
// 128 o x 128 px tile, K = 9 taps x 512 c, BK=32, 2-phase double buffer.
// All per-lane addresses hoisted; per-step offset is wave-uniform SALU only.
__device__ __forceinline__ void gload16(const void* g, void* l) {
    __builtin_amdgcn_global_load_lds(
        (const __attribute__((address_space(1))) unsigned*)g,
        (__attribute__((address_space(3))) unsigned*)l, 16, 0, 0);
}

__global__ __launch_bounds__(256) void k_conv_mfma(
    const __hip_bfloat16* __restrict__ wb, const __hip_bfloat16* __restrict__ xt,
    const float* __restrict__ coef, const float* __restrict__ bias,
    __hip_bfloat16* __restrict__ y1)
{
    __shared__ __hip_bfloat16 lds[2][2][128][32];     // [buf][A|B][row][c]

    // bijective XCD swizzle (1120 % 8 == 0): each XCD gets 140 consecutive
    // flat ids; o-major order keeps one 1.18 MB wb panel L2-resident per chunk.
    int flat = blockIdx.x + 35 * (blockIdx.y + 4 * blockIdx.z);
    { int xcd = flat & 7, idx = flat >> 3; flat = xcd * 140 + idx; }
    const int pi = flat % 35;
    const int t2 = flat / 35;                         // 0..31: (oi*8 + b)
    const int b  = t2 & 7;
    const int o0 = (t2 >> 3) * 128;
    const int p0 = pi * 128;

    const int tid = threadIdx.x, wv = tid >> 6, ln = tid & 63;
    const int wm = wv >> 1, wn = wv & 1;

    // ---- per-lane staging base addresses (loop-invariant) ----
    const char* baseA[2];
    const char* baseB[2];
    #pragma unroll
    for (int i = 0; i < 2; ++i) {
        int j = i * 256 + wv * 64 + ln;
        int row = j >> 2, sl = j & 3;
        baseA[i] = (const char*)(wb + (size_t)(o0 + row) * 512
                                 + ((sl ^ ((row >> 1) & 3)) << 3));
        int p = p0 + row; if (p > NPIX - 1) p = NPIX - 1;
        int py = (int)(((unsigned)p * 63551u) >> 22); // p/66
        int px = p - py * 66;
        baseB[i] = (const char*)(xt + (size_t)b * XP * XP * 512
                                 + (size_t)(py * XP + px) * 512
                                 + ((sl ^ ((row >> 1) & 3)) << 3));
    }

    // ---- per-lane LDS fragment element offsets (loop-invariant) ----
    int aoff[4], boff[4];
    #pragma unroll
    for (int f = 0; f < 4; ++f) {
        int r  = wm * 64 + f * 16 + (ln & 15);
        aoff[f] = r * 32 + (((ln >> 4) ^ ((r >> 1) & 3)) << 3);
        int rb = wn * 64 + f * 16 + (ln & 15);
        boff[f] = rb * 32 + (((ln >> 4) ^ ((rb >> 1) & 3)) << 3);
    }

    f4v acc[4][4];
    #pragma unroll
    for (int fm = 0; fm < 4; ++fm)
        #pragma unroll
        for (int fn = 0; fn < 4; ++fn) acc[fm][fn] = (f4v){0.f, 0.f, 0.f, 0.f};

    auto stage = [&](int st, int buf) {
        int tap = st >> 4;                            // uniform -> SALU
        int ki  = (tap * 11) >> 5;                    // tap/3 for tap<9
        int kj  = tap - ki * 3;
        unsigned ccb  = (unsigned)(st & 15) << 6;     // c-chunk bytes
        unsigned offA = (unsigned)tap * 524288u + ccb;            // tap*512*512*2B
        unsigned offB = (unsigned)(ki * XP + kj) * 1024u + ccb;   // (ki*XP+kj)*512*2B
        __hip_bfloat16* dA = &lds[buf][0][0][0] + (size_t)wv * 512;
        __hip_bfloat16* dB = &lds[buf][1][0][0] + (size_t)wv * 512;
        #pragma unroll
        for (int i = 0; i < 2; ++i) {
            gload16(baseA[i] + offA, dA + i * 2048);
            gload16(baseB[i] + offB, dB + i * 2048);
        }
    };

    stage(0, 0);
    __syncthreads();

    for (int st = 0; st < 144; ++st) {
        const int cur = st & 1;
        if (st != 143) stage(st + 1, cur ^ 1);
        const __hip_bfloat16* A  = &lds[cur][0][0][0];
        const __hip_bfloat16* Bm = &lds[cur][1][0][0];
        s8v af[4], bfv[4];
        #pragma unroll
        for (int f = 0; f < 4; ++f) {
            af[f]  = *reinterpret_cast<const s8v*>(A  + aoff[f]);
            bfv[f] = *reinterpret_cast<const s8v*>(Bm + boff[f]);
        }
        #pragma unroll
        for (int fm = 0; fm < 4; ++fm)
            #pragma unroll
            for (int fn = 0; fn < 4; ++fn)
                acc[fm][fn] = __builtin_amdgcn_mfma_f32_16x16x32_bf16(
                    af[fm], bfv[fn], acc[fm][fn], 0, 0, 0);
        __syncthreads();
    }

    // epilogue: y1[b][o][p] bf16 = acc*coef + bias
    #pragma unroll
    for (int fm = 0; fm < 4; ++fm) {
        #pragma unroll
        for (int fn = 0; fn < 4; ++fn) {
            int p = p0 + wn * 64 + fn * 16 + (ln & 15);
            if (p < NPIX) {
                int ob = o0 + wm * 64 + fm * 16 + (ln >> 4) * 4;
                #pragma unroll
                for (int j = 0; j < 4; ++j) {
                    int o = ob + j;
                    float v = acc[fm][fn][j] * coef[b * 512 + o] + bias[o];
                    y1[((size_t)(b * 512 + o)) * NPIX + p] = __float2bfloat16(v);
                }
            }
        }
    }
}

// ---------------- fused upfirdn2(up2,pad(9,8)) -> lrelu*sqrt2,clamp -> upfirdn2(down2) ----
// 32x32 output tile. No integer div/mod; polyphase even/odd pair sharing
// (both parities share tap base (rc>>1)+5, only the coef set differs);
// float2 LDS reads in the down phases; It/zt and hu/dh share LDS regions.
__global__ __launch_bounds__(256) void k_style_fir(
    const __hip_bfloat16* __restrict__ y1, const float* __restrict__ uf,
    const float* __restrict__ df, float* __restrict__ out)
{
    __shared__ float smA[5632];          // It[42][44] then zt[74][76]
    __shared__ float smB[3200];          // hu[42][76] then dh[74][36]
    float* It = smA;                     // stride 44
    float* hu = smB;                     // stride 76
    float* zt = smA;                     // stride 76
    float* dh = smB;                     // stride 36

    const int img = blockIdx.z;          // b*COUT + o
    const int oy0 = blockIdx.y * 32;
    const int ox0 = blockIdx.x * 32;
    const int tid = threadIdx.x;
    const __hip_bfloat16* I = y1 + (size_t)img * NPIX;

    float cu[12], cd[12];
    #pragma unroll
    for (int q = 0; q < 12; ++q) { cu[q] = uf[q]; cd[q] = df[q]; }

    const int ty = tid >> 5, tx = tid & 31;   // 8 x 32
    const int ty4 = tid >> 4, tx4 = tid & 15; // 16 x 16

    // phase 0: load It[42][42] <- y1 tile rows/cols [oy0-4, oy0+37]
    #pragma unroll
    for (int k = 0; k < 6; ++k) {
        int rr = ty + 8 * k; if (rr >= 42) break;
        int gy = oy0 - 4 + rr;
        bool yin = (gy >= 0 && gy < HO_);
        #pragma unroll
        for (int j = 0; j < 2; ++j) {
            int cc = tx + 32 * j; if (cc >= 42) continue;
            int gx = ox0 - 4 + cc;
            float v = 0.f;
            if (yin && gx >= 0 && gx < HO_) v = __bfloat162float(I[gy * HO_ + gx]);
            It[rr * 44 + cc] = v;
        }
    }
    __syncthreads();

    // phase 1: horizontal up-filter, 2 outputs (parities) per 6 reads.
    // hu[m][2h+p] = 2 * sum_q uf[2q+p] * It[m][h+5-q]
    #pragma unroll
    for (int k = 0; k < 6; ++k) {
        int m = ty + 8 * k; if (m >= 42) break;
        #pragma unroll
        for (int j = 0; j < 2; ++j) {
            int h = tx + 32 * j; if (h >= 37) continue;
            float v[6];
            #pragma unroll
            for (int q = 0; q < 6; ++q) v[q] = It[m * 44 + h + 5 - q];
            float e = 0.f, o = 0.f;
            #pragma unroll
            for (int q = 0; q < 6; ++q) { e += cu[2 * q] * v[q]; o += cu[2 * q + 1] * v[q]; }
            *reinterpret_cast<float2*>(hu + m * 76 + 2 * h) = make_float2(2.f * e, 2.f * o);
        }
    }
    __syncthreads();

    // phase 2: vertical up-filter + lrelu*sqrt2 + clamp, 2 rows per 6 reads.
    #pragma unroll
    for (int k = 0; k < 5; ++k) {
        int r = ty + 8 * k; if (r >= 37) break;
        #pragma unroll
        for (int j = 0; j < 3; ++j) {
            int rx = tx + 32 * j; if (rx >= 74) continue;
            float v[6];
            #pragma unroll
            for (int q = 0; q < 6; ++q) v[q] = hu[(r + 5 - q) * 76 + rx];
            float e = 0.f, o = 0.f;
            #pragma unroll
            for (int q = 0; q < 6; ++q) { e += cu[2 * q] * v[q]; o += cu[2 * q + 1] * v[q]; }
            e *= 2.f; o *= 2.f;
            e = (e >= 0.f ? e : e * 0.2f) * 1.4142135623730951f;
            o = (o >= 0.f ? o : o * 0.2f) * 1.4142135623730951f;
            e = fminf(fmaxf(e, -256.f), 256.f);
            o = fminf(fmaxf(o, -256.f), 256.f);
            zt[(2 * r) * 76 + rx] = e;
            zt[(2 * r + 1) * 76 + rx] = o;
        }
    }
    __syncthreads();

    // phase 3: down horizontal (+decimate x), 2 adjacent outputs per 7 float2 reads.
    // dh[ry][2t+s] = sum_u zt[ry][4t+2s+u] * df[11-u]
    #pragma unroll
    for (int k = 0; k < 5; ++k) {
        int ry = ty4 + 16 * k; if (ry >= 74) break;
        const float* zr = zt + ry * 76 + 4 * tx4;
        float z[14];
        #pragma unroll
        for (int t = 0; t < 7; ++t) {
            float2 p2 = *reinterpret_cast<const float2*>(zr + 2 * t);
            z[2 * t] = p2.x; z[2 * t + 1] = p2.y;
        }
        float a0 = 0.f, a1 = 0.f;
        #pragma unroll
        for (int u = 0; u < 12; ++u) { a0 += z[u] * cd[11 - u]; a1 += z[u + 2] * cd[11 - u]; }
        *reinterpret_cast<float2*>(dh + ry * 36 + 2 * tx4) = make_float2(a0, a1);
    }
    __syncthreads();

    // phase 4: down vertical (+decimate y) + store, 2 rows per 14 reads.
    #pragma unroll
    for (int k = 0; k < 2; ++k) {
        int r2 = ty + 8 * k;                 // oy pair = (2*r2, 2*r2+1)
        float d[14];
        #pragma unroll
        for (int v = 0; v < 14; ++v) d[v] = dh[(4 * r2 + v) * 36 + tx];
        float a0 = 0.f, a1 = 0.f;
        #pragma unroll
        for (int v = 0; v < 12; ++v) { a0 += d[v] * cd[11 - v]; a1 += d[v + 2] * cd[11 - v]; }
        float* op = out + (size_t)img * 64 * 64 + (oy0 + 2 * r2) * 64 + ox0 + tx;
        op[0]  = a0;
        op[64] = a1;
    }
}

extern "C" void kernel_launch(void* const* d_in, const int* in_sizes, int n_in,
                              void* d_out, int out_size, void* d_ws, size_t ws_size,
                              hipStream_t stream) {
    const float* x    = (const float*)d_in[0];
    const float* w    = (const float*)d_in[1];
    const float* aw   = (const float*)d_in[2];
    const float* ab   = (const float*)d_in[3];
    const float* cw   = (const float*)d_in[4];
    const float* bias = (const float*)d_in[5];
    const float* uf   = (const float*)d_in[6];
    const float* df   = (const float*)d_in[7];
    const float* ema  = (const float*)d_in[8];
    float* out = (float*)d_out;

    float* ws   = (float*)d_ws;
    float* s_   = ws;                                   // 4096
    float* coef = ws + 4096;                            // 4096
    float* r_   = ws + 8192;                            // 262144
    // bf16 regions (sizes in float-slots): y1 8,921,088 | xt 9,469,952 | wb 1,179,648
    __hip_bfloat16* y1 = (__hip_bfloat16*)(ws + 270336);
    __hip_bfloat16* xt = (__hip_bfloat16*)(ws + 270336 + 8921088);
    __hip_bfloat16* wb = (__hip_bfloat16*)(ws + 270336 + 8921088 + 9469952);

    k_style_s   <<<16,   256, 0, stream>>>(w, aw, ab, s_);
    k_style_r   <<<1024, 256, 0, stream>>>(cw, r_);
    k_style_coef<<<16,   256, 0, stream>>>(s_, r_, ema, coef);
    k_prep_w    <<<9216, 256, 0, stream>>>(cw, wb);
    k_prep_x    <<<dim3(68, 8), 256, 0, stream>>>(x, s_, xt);
    k_conv_mfma <<<dim3(35, 4, 8), 256, 0, stream>>>(wb, xt, coef, bias, y1);
    k_style_fir <<<dim3(2, 2, 4096), 256, 0, stream>>>(y1, uf, df, out);
}

// Round 8
// 463.459 us; speedup vs baseline: 1.4090x; 1.0274x over previous
//
#include <hip/hip_runtime.h>
#include <hip/hip_bf16.h>

// StyleLayer: modulated conv3x3 as bf16 MFMA implicit GEMM (demod folded into
// input/output scales) + fused polyphase upfirdn(up2)->lrelu/clamp->upfirdn(down2).
// B=8, CIN=COUT=SDIM=512, H=W=64, K=3, taps=12, out 64x64. Conv out 66x66 (=4356 px).

#define B_    8
#define CIN_  512
#define COUT_ 512
#define SDIM_ 512
#define H_    64
#define W_    64
#define HO_   66
#define NPIX  4356          // 66*66
#define XP    68            // padded input spatial (origin shift 2)

typedef short s8v  __attribute__((ext_vector_type(8)));   // 8 bf16 in 4 VGPRs
typedef float f4v  __attribute__((ext_vector_type(4)));

// ---------------- s[b,c] = w @ (aw/sqrt(SDIM)).T + ab ----------------
__global__ void k_style_s(const float* __restrict__ w, const float* __restrict__ aw,
                          const float* __restrict__ ab, float* __restrict__ s) {
    int t = blockIdx.x * blockDim.x + threadIdx.x;    // 4096 = b*512+c
    int b = t >> 9, c = t & 511;
    const float inv = 0.044194173824159216f;          // 1/sqrt(512)
    const float* wp = w + b * SDIM_;
    const float* ap = aw + c * SDIM_;
    float acc = 0.f;
    for (int k = 0; k < SDIM_; ++k) acc += wp[k] * ap[k];
    s[t] = acc * inv + ab[c];
}

// ---------------- r[o,c] = sum_k cw[o,c,k]^2 ----------------
__global__ void k_style_r(const float* __restrict__ cw, float* __restrict__ r) {
    int t = blockIdx.x * blockDim.x + threadIdx.x;    // 262144 = o*512+c
    const float* p = cw + t * 9;
    float a = 0.f;
    #pragma unroll
    for (int k = 0; k < 9; ++k) a += p[k] * p[k];
    r[t] = a;
}

// ---------------- coef[b,o] = scale * d[b,o] * rsqrt(ema) ----------------
__global__ void k_style_coef(const float* __restrict__ s, const float* __restrict__ r,
                             const float* __restrict__ ema, float* __restrict__ coef) {
    int t = blockIdx.x * blockDim.x + threadIdx.x;    // 4096 = b*512+o
    int b = t >> 9, o = t & 511;
    const float scale2 = 1.0f / 4608.0f;
    const float* sp = s + b * 512;
    const float* rp = r + o * 512;
    float acc = 0.f;
    for (int c = 0; c < 512; ++c) { float sv = sp[c]; acc += sv * sv * rp[c]; }
    float d  = rsqrtf(scale2 * acc + 1e-8f);
    float ig = rsqrtf(ema[0]);
    coef[t] = d * ig * 0.014731391274719739f;         // * 1/sqrt(4608)
}

// ---------------- wb[tap][o][c] = bf16(cw[o][c][tap]) ----------------
__global__ __launch_bounds__(256) void k_prep_w(const float* __restrict__ cw,
                                                __hip_bfloat16* __restrict__ wb) {
    int t = blockIdx.x * 256 + threadIdx.x;           // 9*512*512 = 2359296
    int tap = t / (512 * 512);
    int rem = t - tap * 512 * 512;
    int o = rem >> 9, c = rem & 511;
    wb[t] = __float2bfloat16(cw[(o * 512 + c) * 9 + tap]);
}

// ---------------- xt[b][y][x][c] = bf16(x[b][c][y-2][x-2] * s[b][c]), zero pad ----
__global__ __launch_bounds__(256) void k_prep_x(const float* __restrict__ x,
                                                const float* __restrict__ s,
                                                __hip_bfloat16* __restrict__ xt) {
    __shared__ float tile[64][65];
    const int y = blockIdx.x;            // 0..67
    const int b = blockIdx.y;
    const int tid = threadIdx.x;
    const bool yin = (y >= 2 && y < 66);
    __hip_bfloat16* orow = xt + ((size_t)(b * XP + y)) * XP * 512;
    for (int c0 = 0; c0 < 512; c0 += 64) {
        if (yin) {
            for (int i = tid; i < 64 * 64; i += 256) {
                int c = i >> 6, xx = i & 63;
                tile[c][xx] = x[(((size_t)b * 512 + c0 + c) * 64 + (y - 2)) * 64 + xx]
                              * s[b * 512 + c0 + c];
            }
        }
        __syncthreads();
        for (int j = tid; j < 68 * 8; j += 256) {     // 68 x-positions, 8 c-groups of 8
            int xx = j >> 3, cg = j & 7;
            bool xin = yin && (xx >= 2 && xx < 66);
            union { ushort u[8]; float4 f4; } pk;
            #pragma unroll
            for (int k = 0; k < 8; ++k) {
                float v = xin ? tile[cg * 8 + k][xx - 2] : 0.f;
                __hip_bfloat16 h = __float2bfloat16(v);
                pk.u[k] = *reinterpret_cast<ushort*>(&h);
            }
            *reinterpret_cast<float4*>(orow + (size_t)xx * 512 + c0 + cg * 8) = pk.f4;
        }
        __syncthreads();
    }
}

// ---------------- MFMA implicit-GEMM conv ----------------
// 128 o x 128 px tile, K = 9 taps x 512 c, BK=32, 2-phase double buffer,
// manual unroll-by-2 (compile-time buffer indices) + saddr-form staging
// (uniform SGPR base + 32-bit per-lane voffset).
__device__ __forceinline__ void gload16u(const char* base, unsigned voff, void* l) {
    __builtin_amdgcn_global_load_lds(
        (const __attribute__((address_space(1))) unsigned*)(base + voff),
        (__attribute__((address_space(3))) unsigned*)l, 16, 0, 0);
}

__global__ __launch_bounds__(256) void k_conv_mfma(
    const __hip_bfloat16* __restrict__ wb, const __hip_bfloat16* __restrict__ xt,
    const float* __restrict__ coef, const float* __restrict__ bias,
    __hip_bfloat16* __restrict__ y1)
{
    __shared__ __hip_bfloat16 lds[2][2][128][32];     // [buf][A|B][row][c]

    // bijective XCD swizzle (1120 % 8 == 0): each XCD gets 140 consecutive
    // flat ids; o-major order keeps one 1.18 MB wb panel L2-resident per chunk.
    int flat = blockIdx.x + 35 * (blockIdx.y + 4 * blockIdx.z);
    { int xcd = flat & 7, idx = flat >> 3; flat = xcd * 140 + idx; }
    const int pi = flat % 35;
    const int t2 = flat / 35;                         // 0..31: (oi*8 + b)
    const int b  = t2 & 7;
    const int o0 = (t2 >> 3) * 128;
    const int p0 = pi * 128;

    const int tid = threadIdx.x, wv = tid >> 6, ln = tid & 63;
    const int wm = wv >> 1, wn = wv & 1;

    // ---- per-lane 32-bit staging offsets (loop-invariant), uniform bases ----
    const char* wbB = (const char*)wb;
    const char* xtB = (const char*)(xt + (size_t)b * XP * XP * 512);
    unsigned voffA[2], voffB[2];
    #pragma unroll
    for (int i = 0; i < 2; ++i) {
        int j = i * 256 + wv * 64 + ln;
        int row = j >> 2, sl = j & 3;
        unsigned swz = (unsigned)((sl ^ ((row >> 1) & 3)) << 3);
        voffA[i] = ((unsigned)(o0 + row) * 512u + swz) * 2u;
        int p = p0 + row; if (p > NPIX - 1) p = NPIX - 1;
        int py = (int)(((unsigned)p * 63551u) >> 22); // p/66
        int px = p - py * 66;
        voffB[i] = ((unsigned)(py * XP + px) * 512u + swz) * 2u;
    }

    // ---- per-lane LDS fragment byte offsets (loop-invariant) ----
    int aoff[4], boff[4];
    #pragma unroll
    for (int f = 0; f < 4; ++f) {
        int r  = wm * 64 + f * 16 + (ln & 15);
        aoff[f] = (r * 32 + (((ln >> 4) ^ ((r >> 1) & 3)) << 3)) * 2;
        int rb = wn * 64 + f * 16 + (ln & 15);
        boff[f] = (rb * 32 + (((ln >> 4) ^ ((rb >> 1) & 3)) << 3)) * 2;
    }

    f4v acc[4][4];
    #pragma unroll
    for (int fm = 0; fm < 4; ++fm)
        #pragma unroll
        for (int fn = 0; fn < 4; ++fn) acc[fm][fn] = (f4v){0.f, 0.f, 0.f, 0.f};

    auto stage = [&](int st, int buf) {               // buf is a literal at call sites
        int tap = st >> 4;                            // uniform -> SALU
        int ki  = (tap * 11) >> 5;                    // tap/3 for tap<9
        int kj  = tap - ki * 3;
        unsigned ccb  = (unsigned)(st & 15) << 6;     // c-chunk bytes
        unsigned offA = (unsigned)tap * 524288u + ccb;            // tap*512*512*2B
        unsigned offB = (unsigned)(ki * XP + kj) * 1024u + ccb;   // (ki*XP+kj)*512*2B
        __hip_bfloat16* dA = &lds[buf][0][0][0] + wv * 512;
        __hip_bfloat16* dB = &lds[buf][1][0][0] + wv * 512;
        gload16u(wbB, voffA[0] + offA, dA);
        gload16u(wbB, voffA[1] + offA, dA + 2048);
        gload16u(xtB, voffB[0] + offB, dB);
        gload16u(xtB, voffB[1] + offB, dB + 2048);
    };

    auto compute = [&](int buf) {                     // buf literal -> const LDS bases
        const char* A  = (const char*)&lds[buf][0][0][0];
        const char* Bm = (const char*)&lds[buf][1][0][0];
        s8v af[4], bfv[4];
        #pragma unroll
        for (int f = 0; f < 4; ++f) {
            af[f]  = *reinterpret_cast<const s8v*>(A  + aoff[f]);
            bfv[f] = *reinterpret_cast<const s8v*>(Bm + boff[f]);
        }
        #pragma unroll
        for (int fm = 0; fm < 4; ++fm)
            #pragma unroll
            for (int fn = 0; fn < 4; ++fn)
                acc[fm][fn] = __builtin_amdgcn_mfma_f32_16x16x32_bf16(
                    af[fm], bfv[fn], acc[fm][fn], 0, 0, 0);
    };

    stage(0, 0);
    __syncthreads();

    #pragma unroll 1
    for (int st = 0; st < 144; st += 2) {
        stage(st + 1, 1);                             // st+1 <= 143 always
        compute(0);
        __syncthreads();
        if (st != 142) stage(st + 2, 0);
        compute(1);
        __syncthreads();
    }

    // epilogue: y1[b][o][p] bf16 = acc*coef + bias
    #pragma unroll
    for (int fm = 0; fm < 4; ++fm) {
        #pragma unroll
        for (int fn = 0; fn < 4; ++fn) {
            int p = p0 + wn * 64 + fn * 16 + (ln & 15);
            if (p < NPIX) {
                int ob = o0 + wm * 64 + fm * 16 + (ln >> 4) * 4;
                #pragma unroll
                for (int j = 0; j < 4; ++j) {
                    int o = ob + j;
                    float v = acc[fm][fn][j] * coef[b * 512 + o] + bias[o];
                    y1[((size_t)(b * 512 + o)) * NPIX + p] = __float2bfloat16(v);
                }
            }
        }
    }
}

// ---------------- fused upfirdn2(up2,pad(9,8)) -> lrelu*sqrt2,clamp -> upfirdn2(down2) ----
// 32x32 output tile. No integer div/mod; polyphase even/odd pair sharing
// (both parities share tap base (rc>>1)+5, only the coef set differs);
// float2 LDS reads in the down phases; It/zt and hu/dh share LDS regions.
__global__ __launch_bounds__(256) void k_style_fir(
    const __hip_bfloat16* __restrict__ y1, const float* __restrict__ uf,
    const float* __restrict__ df, float* __restrict__ out)
{
    __shared__ float smA[5632];          // It[42][44] then zt[74][76]
    __shared__ float smB[3200];          // hu[42][76] then dh[74][36]
    float* It = smA;                     // stride 44
    float* hu = smB;                     // stride 76
    float* zt = smA;                     // stride 76
    float* dh = smB;                     // stride 36

    const int img = blockIdx.z;          // b*COUT + o
    const int oy0 = blockIdx.y * 32;
    const int ox0 = blockIdx.x * 32;
    const int tid = threadIdx.x;
    const __hip_bfloat16* I = y1 + (size_t)img * NPIX;

    float cu[12], cd[12];
    #pragma unroll
    for (int q = 0; q < 12; ++q) { cu[q] = uf[q]; cd[q] = df[q]; }

    const int ty = tid >> 5, tx = tid & 31;   // 8 x 32
    const int ty4 = tid >> 4, tx4 = tid & 15; // 16 x 16

    // phase 0: load It[42][42] <- y1 tile rows/cols [oy0-4, oy0+37]
    #pragma unroll
    for (int k = 0; k < 6; ++k) {
        int rr = ty + 8 * k; if (rr >= 42) break;
        int gy = oy0 - 4 + rr;
        bool yin = (gy >= 0 && gy < HO_);
        #pragma unroll
        for (int j = 0; j < 2; ++j) {
            int cc = tx + 32 * j; if (cc >= 42) continue;
            int gx = ox0 - 4 + cc;
            float v = 0.f;
            if (yin && gx >= 0 && gx < HO_) v = __bfloat162float(I[gy * HO_ + gx]);
            It[rr * 44 + cc] = v;
        }
    }
    __syncthreads();

    // phase 1: horizontal up-filter, 2 outputs (parities) per 6 reads.
    // hu[m][2h+p] = 2 * sum_q uf[2q+p] * It[m][h+5-q]
    #pragma unroll
    for (int k = 0; k < 6; ++k) {
        int m = ty + 8 * k; if (m >= 42) break;
        #pragma unroll
        for (int j = 0; j < 2; ++j) {
            int h = tx + 32 * j; if (h >= 37) continue;
            float v[6];
            #pragma unroll
            for (int q = 0; q < 6; ++q) v[q] = It[m * 44 + h + 5 - q];
            float e = 0.f, o = 0.f;
            #pragma unroll
            for (int q = 0; q < 6; ++q) { e += cu[2 * q] * v[q]; o += cu[2 * q + 1] * v[q]; }
            *reinterpret_cast<float2*>(hu + m * 76 + 2 * h) = make_float2(2.f * e, 2.f * o);
        }
    }
    __syncthreads();

    // phase 2: vertical up-filter + lrelu*sqrt2 + clamp, 2 rows per 6 reads.
    #pragma unroll
    for (int k = 0; k < 5; ++k) {
        int r = ty + 8 * k; if (r >= 37) break;
        #pragma unroll
        for (int j = 0; j < 3; ++j) {
            int rx = tx + 32 * j; if (rx >= 74) continue;
            float v[6];
            #pragma unroll
            for (int q = 0; q < 6; ++q) v[q] = hu[(r + 5 - q) * 76 + rx];
            float e = 0.f, o = 0.f;
            #pragma unroll
            for (int q = 0; q < 6; ++q) { e += cu[2 * q] * v[q]; o += cu[2 * q + 1] * v[q]; }
            e *= 2.f; o *= 2.f;
            e = (e >= 0.f ? e : e * 0.2f) * 1.4142135623730951f;
            o = (o >= 0.f ? o : o * 0.2f) * 1.4142135623730951f;
            e = fminf(fmaxf(e, -256.f), 256.f);
            o = fminf(fmaxf(o, -256.f), 256.f);
            zt[(2 * r) * 76 + rx] = e;
            zt[(2 * r + 1) * 76 + rx] = o;
        }
    }
    __syncthreads();

    // phase 3: down horizontal (+decimate x), 2 adjacent outputs per 7 float2 reads.
    // dh[ry][2t+s] = sum_u zt[ry][4t+2s+u] * df[11-u]
    #pragma unroll
    for (int k = 0; k < 5; ++k) {
        int ry = ty4 + 16 * k; if (ry >= 74) break;
        const float* zr = zt + ry * 76 + 4 * tx4;
        float z[14];
        #pragma unroll
        for (int t = 0; t < 7; ++t) {
            float2 p2 = *reinterpret_cast<const float2*>(zr + 2 * t);
            z[2 * t] = p2.x; z[2 * t + 1] = p2.y;
        }
        float a0 = 0.f, a1 = 0.f;
        #pragma unroll
        for (int u = 0; u < 12; ++u) { a0 += z[u] * cd[11 - u]; a1 += z[u + 2] * cd[11 - u]; }
        *reinterpret_cast<float2*>(dh + ry * 36 + 2 * tx4) = make_float2(a0, a1);
    }
    __syncthreads();

    // phase 4: down vertical (+decimate y) + store, 2 rows per 14 reads.
    #pragma unroll
    for (int k = 0; k < 2; ++k) {
        int r2 = ty + 8 * k;                 // oy pair = (2*r2, 2*r2+1)
        float d[14];
        #pragma unroll
        for (int v = 0; v < 14; ++v) d[v] = dh[(4 * r2 + v) * 36 + tx];
        float a0 = 0.f, a1 = 0.f;
        #pragma unroll
        for (int v = 0; v < 12; ++v) { a0 += d[v] * cd[11 - v]; a1 += d[v + 2] * cd[11 - v]; }
        float* op = out + (size_t)img * 64 * 64 + (oy0 + 2 * r2) * 64 + ox0 + tx;
        op[0]  = a0;
        op[64] = a1;
    }
}

extern "C" void kernel_launch(void* const* d_in, const int* in_sizes, int n_in,
                              void* d_out, int out_size, void* d_ws, size_t ws_size,
                              hipStream_t stream) {
    const float* x    = (const float*)d_in[0];
    const float* w    = (const float*)d_in[1];
    const float* aw   = (const float*)d_in[2];
    const float* ab   = (const float*)d_in[3];
    const float* cw   = (const float*)d_in[4];
    const float* bias = (const float*)d_in[5];
    const float* uf   = (const float*)d_in[6];
    const float* df   = (const float*)d_in[7];
    const float* ema  = (const float*)d_in[8];
    float* out = (float*)d_out;

    float* ws   = (float*)d_ws;
    float* s_   = ws;                                   // 4096
    float* coef = ws + 4096;                            // 4096
    float* r_   = ws + 8192;                            // 262144
    // bf16 regions (sizes in float-slots): y1 8,921,088 | xt 9,469,952 | wb 1,179,648
    __hip_bfloat16* y1 = (__hip_bfloat16*)(ws + 270336);
    __hip_bfloat16* xt = (__hip_bfloat16*)(ws + 270336 + 8921088);
    __hip_bfloat16* wb = (__hip_bfloat16*)(ws + 270336 + 8921088 + 9469952);

    k_style_s   <<<16,   256, 0, stream>>>(w, aw, ab, s_);
    k_style_r   <<<1024, 256, 0, stream>>>(cw, r_);
    k_style_coef<<<16,   256, 0, stream>>>(s_, r_, ema, coef);
    k_prep_w    <<<9216, 256, 0, stream>>>(cw, wb);
    k_prep_x    <<<dim3(68, 8), 256, 0, stream>>>(x, s_, xt);
    k_conv_mfma <<<dim3(35, 4, 8), 256, 0, stream>>>(wb, xt, coef, bias, y1);
    k_style_fir <<<dim3(2, 2, 4096), 256, 0, stream>>>(y1, uf, df, out);
}

// Round 9
// 439.770 us; speedup vs baseline: 1.4849x; 1.0539x over previous
//
#include <hip/hip_runtime.h>
#include <hip/hip_bf16.h>

// StyleLayer: modulated conv3x3 as bf16 MFMA implicit GEMM (demod folded into
// input/output scales) + fused polyphase upfirdn(up2)->lrelu/clamp->upfirdn(down2).
// B=8, CIN=COUT=SDIM=512, H=W=64, K=3, taps=12, out 64x64. Conv out 66x66 (=4356 px).

#define B_    8
#define CIN_  512
#define COUT_ 512
#define SDIM_ 512
#define H_    64
#define W_    64
#define HO_   66
#define NPIX  4356          // 66*66
#define XP    68            // padded input spatial (origin shift 2)

typedef short s8v  __attribute__((ext_vector_type(8)));   // 8 bf16 in 4 VGPRs
typedef float f4v  __attribute__((ext_vector_type(4)));

// ---------------- s[b,c] = w @ (aw/sqrt(SDIM)).T + ab ----------------
__global__ void k_style_s(const float* __restrict__ w, const float* __restrict__ aw,
                          const float* __restrict__ ab, float* __restrict__ s) {
    int t = blockIdx.x * blockDim.x + threadIdx.x;    // 4096 = b*512+c
    int b = t >> 9, c = t & 511;
    const float inv = 0.044194173824159216f;          // 1/sqrt(512)
    const float* wp = w + b * SDIM_;
    const float* ap = aw + c * SDIM_;
    float acc = 0.f;
    for (int k = 0; k < SDIM_; ++k) acc += wp[k] * ap[k];
    s[t] = acc * inv + ab[c];
}

// ---------------- r[o,c] = sum_k cw[o,c,k]^2 ----------------
__global__ void k_style_r(const float* __restrict__ cw, float* __restrict__ r) {
    int t = blockIdx.x * blockDim.x + threadIdx.x;    // 262144 = o*512+c
    const float* p = cw + t * 9;
    float a = 0.f;
    #pragma unroll
    for (int k = 0; k < 9; ++k) a += p[k] * p[k];
    r[t] = a;
}

// ---------------- coef[b,o] = scale * d[b,o] * rsqrt(ema) ----------------
__global__ void k_style_coef(const float* __restrict__ s, const float* __restrict__ r,
                             const float* __restrict__ ema, float* __restrict__ coef) {
    int t = blockIdx.x * blockDim.x + threadIdx.x;    // 4096 = b*512+o
    int b = t >> 9, o = t & 511;
    const float scale2 = 1.0f / 4608.0f;
    const float* sp = s + b * 512;
    const float* rp = r + o * 512;
    float acc = 0.f;
    for (int c = 0; c < 512; ++c) { float sv = sp[c]; acc += sv * sv * rp[c]; }
    float d  = rsqrtf(scale2 * acc + 1e-8f);
    float ig = rsqrtf(ema[0]);
    coef[t] = d * ig * 0.014731391274719739f;         // * 1/sqrt(4608)
}

// ---------------- wb[tap][o][c] = bf16(cw[o][c][tap]) ----------------
__global__ __launch_bounds__(256) void k_prep_w(const float* __restrict__ cw,
                                                __hip_bfloat16* __restrict__ wb) {
    int t = blockIdx.x * 256 + threadIdx.x;           // 9*512*512 = 2359296
    int tap = t / (512 * 512);
    int rem = t - tap * 512 * 512;
    int o = rem >> 9, c = rem & 511;
    wb[t] = __float2bfloat16(cw[(o * 512 + c) * 9 + tap]);
}

// ---------------- xt[b][y][x][c] = bf16(x[b][c][y-2][x-2] * s[b][c]), zero pad ----
__global__ __launch_bounds__(256) void k_prep_x(const float* __restrict__ x,
                                                const float* __restrict__ s,
                                                __hip_bfloat16* __restrict__ xt) {
    __shared__ float tile[64][65];
    const int y = blockIdx.x;            // 0..67
    const int b = blockIdx.y;
    const int tid = threadIdx.x;
    const bool yin = (y >= 2 && y < 66);
    __hip_bfloat16* orow = xt + ((size_t)(b * XP + y)) * XP * 512;
    for (int c0 = 0; c0 < 512; c0 += 64) {
        if (yin) {
            for (int i = tid; i < 64 * 64; i += 256) {
                int c = i >> 6, xx = i & 63;
                tile[c][xx] = x[(((size_t)b * 512 + c0 + c) * 64 + (y - 2)) * 64 + xx]
                              * s[b * 512 + c0 + c];
            }
        }
        __syncthreads();
        for (int j = tid; j < 68 * 8; j += 256) {     // 68 x-positions, 8 c-groups of 8
            int xx = j >> 3, cg = j & 7;
            bool xin = yin && (xx >= 2 && xx < 66);
            union { ushort u[8]; float4 f4; } pk;
            #pragma unroll
            for (int k = 0; k < 8; ++k) {
                float v = xin ? tile[cg * 8 + k][xx - 2] : 0.f;
                __hip_bfloat16 h = __float2bfloat16(v);
                pk.u[k] = *reinterpret_cast<ushort*>(&h);
            }
            *reinterpret_cast<float4*>(orow + (size_t)xx * 512 + c0 + cg * 8) = pk.f4;
        }
        __syncthreads();
    }
}

// ---------------- MFMA implicit-GEMM conv ----------------
// 256 o x 128 px tile, 8 waves (512 thr), K = 9 taps x 512 c, BK=32,
// 2-phase double buffer, manual unroll-by-2, saddr-form staging.
// LDS per buffer: A 256x32 (8192 el) + B 128x32 (4096 el) = 24 KB; x2 = 48 KB.
__device__ __forceinline__ void gload16u(const char* base, unsigned voff, void* l) {
    __builtin_amdgcn_global_load_lds(
        (const __attribute__((address_space(1))) unsigned*)(base + voff),
        (__attribute__((address_space(3))) unsigned*)l, 16, 0, 0);
}

__global__ __launch_bounds__(512) void k_conv_mfma(
    const __hip_bfloat16* __restrict__ wb, const __hip_bfloat16* __restrict__ xt,
    const float* __restrict__ coef, const float* __restrict__ bias,
    __hip_bfloat16* __restrict__ y1)
{
    __shared__ __hip_bfloat16 lds[2][12288];          // [buf][A(8192) | B(4096)]

    // bijective XCD swizzle (560 % 8 == 0): each XCD gets 70 consecutive flat
    // ids = 2 (b,o0) groups x 35 px tiles -> one 2.25 MB A panel L2-resident
    // while B panels stream.
    int flat = blockIdx.x + 35 * (blockIdx.y + 2 * blockIdx.z);
    { int xcd = flat & 7, idx = flat >> 3; flat = xcd * 70 + idx; }
    const int pi = flat % 35;
    const int t2 = flat / 35;                         // 0..15: (oi*8 + b)
    const int b  = t2 & 7;
    const int o0 = (t2 >> 3) * 256;
    const int p0 = pi * 128;

    const int tid = threadIdx.x, wv = tid >> 6, ln = tid & 63;
    const int wm = wv >> 1, wn = wv & 1;              // 4 o-quadrants x 2 px-halves

    // ---- per-lane 32-bit staging offsets (loop-invariant), uniform bases ----
    const char* wbB = (const char*)wb;
    const char* xtB = (const char*)(xt + (size_t)b * XP * XP * 512);
    const int srow = tid >> 2, ssl = tid & 3;         // staging row 0..127, 16B slot
    const unsigned swzs = (unsigned)((ssl ^ ((srow >> 1) & 3)) << 3);
    unsigned voffA0 = ((unsigned)(o0 + srow) * 512u + swzs) * 2u;
    unsigned voffA1 = ((unsigned)(o0 + 128 + srow) * 512u + swzs) * 2u;
    unsigned voffB0;
    {
        int p = p0 + srow; if (p > NPIX - 1) p = NPIX - 1;
        int py = (int)(((unsigned)p * 63551u) >> 22); // p/66
        int px = p - py * 66;
        voffB0 = ((unsigned)(py * XP + px) * 512u + swzs) * 2u;
    }

    // ---- per-lane LDS fragment byte offsets (loop-invariant) ----
    int aoff[4], boff[4];
    #pragma unroll
    for (int f = 0; f < 4; ++f) {
        int r  = wm * 64 + f * 16 + (ln & 15);
        aoff[f] = (r * 32 + (((ln >> 4) ^ ((r >> 1) & 3)) << 3)) * 2;
        int rb = wn * 64 + f * 16 + (ln & 15);
        boff[f] = (8192 + rb * 32 + (((ln >> 4) ^ ((rb >> 1) & 3)) << 3)) * 2;
    }

    f4v acc[4][4];
    #pragma unroll
    for (int fm = 0; fm < 4; ++fm)
        #pragma unroll
        for (int fn = 0; fn < 4; ++fn) acc[fm][fn] = (f4v){0.f, 0.f, 0.f, 0.f};

    auto stage = [&](int st, int buf) {               // buf is a literal at call sites
        int tap = st >> 4;                            // uniform -> SALU
        int ki  = (tap * 11) >> 5;                    // tap/3 for tap<9
        int kj  = tap - ki * 3;
        unsigned ccb  = (unsigned)(st & 15) << 6;     // c-chunk bytes
        unsigned offA = (unsigned)tap * 524288u + ccb;            // tap*512*512*2B
        unsigned offB = (unsigned)(ki * XP + kj) * 1024u + ccb;   // (ki*XP+kj)*512*2B
        __hip_bfloat16* dst = &lds[buf][0] + wv * 512;
        gload16u(wbB, voffA0 + offA, dst);            // A rows   0..127
        gload16u(wbB, voffA1 + offA, dst + 4096);     // A rows 128..255
        gload16u(xtB, voffB0 + offB, dst + 8192);     // B rows   0..127
    };

    auto compute = [&](int buf) {                     // buf literal -> const LDS bases
        const char* base = (const char*)&lds[buf][0];
        s8v af[4], bfv[4];
        #pragma unroll
        for (int f = 0; f < 4; ++f) {
            af[f]  = *reinterpret_cast<const s8v*>(base + aoff[f]);
            bfv[f] = *reinterpret_cast<const s8v*>(base + boff[f]);
        }
        #pragma unroll
        for (int fm = 0; fm < 4; ++fm)
            #pragma unroll
            for (int fn = 0; fn < 4; ++fn)
                acc[fm][fn] = __builtin_amdgcn_mfma_f32_16x16x32_bf16(
                    af[fm], bfv[fn], acc[fm][fn], 0, 0, 0);
    };

    stage(0, 0);
    __syncthreads();

    #pragma unroll 1
    for (int st = 0; st < 144; st += 2) {
        stage(st + 1, 1);                             // st+1 <= 143 always
        compute(0);
        __syncthreads();
        if (st != 142) stage(st + 2, 0);
        compute(1);
        __syncthreads();
    }

    // epilogue: y1[b][o][p] bf16 = acc*coef + bias
    #pragma unroll
    for (int fm = 0; fm < 4; ++fm) {
        #pragma unroll
        for (int fn = 0; fn < 4; ++fn) {
            int p = p0 + wn * 64 + fn * 16 + (ln & 15);
            if (p < NPIX) {
                int ob = o0 + wm * 64 + fm * 16 + (ln >> 4) * 4;
                #pragma unroll
                for (int j = 0; j < 4; ++j) {
                    int o = ob + j;
                    float v = acc[fm][fn][j] * coef[b * 512 + o] + bias[o];
                    y1[((size_t)(b * 512 + o)) * NPIX + p] = __float2bfloat16(v);
                }
            }
        }
    }
}

// ---------------- fused upfirdn2(up2,pad(9,8)) -> lrelu*sqrt2,clamp -> upfirdn2(down2) ----
// 32x32 output tile. No integer div/mod; polyphase even/odd pair sharing
// (both parities share tap base (rc>>1)+5, only the coef set differs);
// float2 LDS reads in the down phases; It/zt and hu/dh share LDS regions.
__global__ __launch_bounds__(256) void k_style_fir(
    const __hip_bfloat16* __restrict__ y1, const float* __restrict__ uf,
    const float* __restrict__ df, float* __restrict__ out)
{
    __shared__ float smA[5632];          // It[42][44] then zt[74][76]
    __shared__ float smB[3200];          // hu[42][76] then dh[74][36]
    float* It = smA;                     // stride 44
    float* hu = smB;                     // stride 76
    float* zt = smA;                     // stride 76
    float* dh = smB;                     // stride 36

    const int img = blockIdx.z;          // b*COUT + o
    const int oy0 = blockIdx.y * 32;
    const int ox0 = blockIdx.x * 32;
    const int tid = threadIdx.x;
    const __hip_bfloat16* I = y1 + (size_t)img * NPIX;

    float cu[12], cd[12];
    #pragma unroll
    for (int q = 0; q < 12; ++q) { cu[q] = uf[q]; cd[q] = df[q]; }

    const int ty = tid >> 5, tx = tid & 31;   // 8 x 32
    const int ty4 = tid >> 4, tx4 = tid & 15; // 16 x 16

    // phase 0: load It[42][42] <- y1 tile rows/cols [oy0-4, oy0+37]
    #pragma unroll
    for (int k = 0; k < 6; ++k) {
        int rr = ty + 8 * k; if (rr >= 42) break;
        int gy = oy0 - 4 + rr;
        bool yin = (gy >= 0 && gy < HO_);
        #pragma unroll
        for (int j = 0; j < 2; ++j) {
            int cc = tx + 32 * j; if (cc >= 42) continue;
            int gx = ox0 - 4 + cc;
            float v = 0.f;
            if (yin && gx >= 0 && gx < HO_) v = __bfloat162float(I[gy * HO_ + gx]);
            It[rr * 44 + cc] = v;
        }
    }
    __syncthreads();

    // phase 1: horizontal up-filter, 2 outputs (parities) per 6 reads.
    // hu[m][2h+p] = 2 * sum_q uf[2q+p] * It[m][h+5-q]
    #pragma unroll
    for (int k = 0; k < 6; ++k) {
        int m = ty + 8 * k; if (m >= 42) break;
        #pragma unroll
        for (int j = 0; j < 2; ++j) {
            int h = tx + 32 * j; if (h >= 37) continue;
            float v[6];
            #pragma unroll
            for (int q = 0; q < 6; ++q) v[q] = It[m * 44 + h + 5 - q];
            float e = 0.f, o = 0.f;
            #pragma unroll
            for (int q = 0; q < 6; ++q) { e += cu[2 * q] * v[q]; o += cu[2 * q + 1] * v[q]; }
            *reinterpret_cast<float2*>(hu + m * 76 + 2 * h) = make_float2(2.f * e, 2.f * o);
        }
    }
    __syncthreads();

    // phase 2: vertical up-filter + lrelu*sqrt2 + clamp, 2 rows per 6 reads.
    #pragma unroll
    for (int k = 0; k < 5; ++k) {
        int r = ty + 8 * k; if (r >= 37) break;
        #pragma unroll
        for (int j = 0; j < 3; ++j) {
            int rx = tx + 32 * j; if (rx >= 74) continue;
            float v[6];
            #pragma unroll
            for (int q = 0; q < 6; ++q) v[q] = hu[(r + 5 - q) * 76 + rx];
            float e = 0.f, o = 0.f;
            #pragma unroll
            for (int q = 0; q < 6; ++q) { e += cu[2 * q] * v[q]; o += cu[2 * q + 1] * v[q]; }
            e *= 2.f; o *= 2.f;
            e = (e >= 0.f ? e : e * 0.2f) * 1.4142135623730951f;
            o = (o >= 0.f ? o : o * 0.2f) * 1.4142135623730951f;
            e = fminf(fmaxf(e, -256.f), 256.f);
            o = fminf(fmaxf(o, -256.f), 256.f);
            zt[(2 * r) * 76 + rx] = e;
            zt[(2 * r + 1) * 76 + rx] = o;
        }
    }
    __syncthreads();

    // phase 3: down horizontal (+decimate x), 2 adjacent outputs per 7 float2 reads.
    // dh[ry][2t+s] = sum_u zt[ry][4t+2s+u] * df[11-u]
    #pragma unroll
    for (int k = 0; k < 5; ++k) {
        int ry = ty4 + 16 * k; if (ry >= 74) break;
        const float* zr = zt + ry * 76 + 4 * tx4;
        float z[14];
        #pragma unroll
        for (int t = 0; t < 7; ++t) {
            float2 p2 = *reinterpret_cast<const float2*>(zr + 2 * t);
            z[2 * t] = p2.x; z[2 * t + 1] = p2.y;
        }
        float a0 = 0.f, a1 = 0.f;
        #pragma unroll
        for (int u = 0; u < 12; ++u) { a0 += z[u] * cd[11 - u]; a1 += z[u + 2] * cd[11 - u]; }
        *reinterpret_cast<float2*>(dh + ry * 36 + 2 * tx4) = make_float2(a0, a1);
    }
    __syncthreads();

    // phase 4: down vertical (+decimate y) + store, 2 rows per 14 reads.
    #pragma unroll
    for (int k = 0; k < 2; ++k) {
        int r2 = ty + 8 * k;                 // oy pair = (2*r2, 2*r2+1)
        float d[14];
        #pragma unroll
        for (int v = 0; v < 14; ++v) d[v] = dh[(4 * r2 + v) * 36 + tx];
        float a0 = 0.f, a1 = 0.f;
        #pragma unroll
        for (int v = 0; v < 12; ++v) { a0 += d[v] * cd[11 - v]; a1 += d[v + 2] * cd[11 - v]; }
        float* op = out + (size_t)img * 64 * 64 + (oy0 + 2 * r2) * 64 + ox0 + tx;
        op[0]  = a0;
        op[64] = a1;
    }
}

extern "C" void kernel_launch(void* const* d_in, const int* in_sizes, int n_in,
                              void* d_out, int out_size, void* d_ws, size_t ws_size,
                              hipStream_t stream) {
    const float* x    = (const float*)d_in[0];
    const float* w    = (const float*)d_in[1];
    const float* aw   = (const float*)d_in[2];
    const float* ab   = (const float*)d_in[3];
    const float* cw   = (const float*)d_in[4];
    const float* bias = (const float*)d_in[5];
    const float* uf   = (const float*)d_in[6];
    const float* df   = (const float*)d_in[7];
    const float* ema  = (const float*)d_in[8];
    float* out = (float*)d_out;

    float* ws   = (float*)d_ws;
    float* s_   = ws;                                   // 4096
    float* coef = ws + 4096;                            // 4096
    float* r_   = ws + 8192;                            // 262144
    // bf16 regions (sizes in float-slots): y1 8,921,088 | xt 9,469,952 | wb 1,179,648
    __hip_bfloat16* y1 = (__hip_bfloat16*)(ws + 270336);
    __hip_bfloat16* xt = (__hip_bfloat16*)(ws + 270336 + 8921088);
    __hip_bfloat16* wb = (__hip_bfloat16*)(ws + 270336 + 8921088 + 9469952);

    k_style_s   <<<16,   256, 0, stream>>>(w, aw, ab, s_);
    k_style_r   <<<1024, 256, 0, stream>>>(cw, r_);
    k_style_coef<<<16,   256, 0, stream>>>(s_, r_, ema, coef);
    k_prep_w    <<<9216, 256, 0, stream>>>(cw, wb);
    k_prep_x    <<<dim3(68, 8), 256, 0, stream>>>(x, s_, xt);
    k_conv_mfma <<<dim3(35, 2, 8), 512, 0, stream>>>(wb, xt, coef, bias, y1);
    k_style_fir <<<dim3(2, 2, 4096), 256, 0, stream>>>(y1, uf, df, out);
}

// Round 10
// 417.271 us; speedup vs baseline: 1.5650x; 1.0539x over previous
//
#include <hip/hip_runtime.h>
#include <hip/hip_bf16.h>

// StyleLayer: modulated conv3x3 as bf16 MFMA implicit GEMM (demod folded into
// input/output scales) + fused polyphase upfirdn(up2)->lrelu/clamp->upfirdn(down2).
// B=8, CIN=COUT=SDIM=512, H=W=64, K=3, taps=12, out 64x64. Conv out 66x66 (=4356 px).

#define B_    8
#define CIN_  512
#define COUT_ 512
#define SDIM_ 512
#define H_    64
#define W_    64
#define HO_   66
#define NPIX  4356          // 66*66
#define XP    68            // padded input spatial (origin shift 2)

typedef short s8v  __attribute__((ext_vector_type(8)));   // 8 bf16 in 4 VGPRs
typedef float f4v  __attribute__((ext_vector_type(4)));

#define WAITV3() asm volatile("s_waitcnt vmcnt(3)" ::: "memory")
#define WAITV0() asm volatile("s_waitcnt vmcnt(0)" ::: "memory")

// ---------------- s[b,c] = w @ (aw/sqrt(SDIM)).T + ab ----------------
__global__ void k_style_s(const float* __restrict__ w, const float* __restrict__ aw,
                          const float* __restrict__ ab, float* __restrict__ s) {
    int t = blockIdx.x * blockDim.x + threadIdx.x;    // 4096 = b*512+c
    int b = t >> 9, c = t & 511;
    const float inv = 0.044194173824159216f;          // 1/sqrt(512)
    const float* wp = w + b * SDIM_;
    const float* ap = aw + c * SDIM_;
    float acc = 0.f;
    for (int k = 0; k < SDIM_; ++k) acc += wp[k] * ap[k];
    s[t] = acc * inv + ab[c];
}

// ---------------- r[o,c] = sum_k cw[o,c,k]^2 ----------------
__global__ void k_style_r(const float* __restrict__ cw, float* __restrict__ r) {
    int t = blockIdx.x * blockDim.x + threadIdx.x;    // 262144 = o*512+c
    const float* p = cw + t * 9;
    float a = 0.f;
    #pragma unroll
    for (int k = 0; k < 9; ++k) a += p[k] * p[k];
    r[t] = a;
}

// ---------------- coef[b,o] = scale * d[b,o] * rsqrt(ema) ----------------
__global__ void k_style_coef(const float* __restrict__ s, const float* __restrict__ r,
                             const float* __restrict__ ema, float* __restrict__ coef) {
    int t = blockIdx.x * blockDim.x + threadIdx.x;    // 4096 = b*512+o
    int b = t >> 9, o = t & 511;
    const float scale2 = 1.0f / 4608.0f;
    const float* sp = s + b * 512;
    const float* rp = r + o * 512;
    float acc = 0.f;
    for (int c = 0; c < 512; ++c) { float sv = sp[c]; acc += sv * sv * rp[c]; }
    float d  = rsqrtf(scale2 * acc + 1e-8f);
    float ig = rsqrtf(ema[0]);
    coef[t] = d * ig * 0.014731391274719739f;         // * 1/sqrt(4608)
}

// ---------------- wb[tap][o][c] = bf16(cw[o][c][tap]) ----------------
__global__ __launch_bounds__(256) void k_prep_w(const float* __restrict__ cw,
                                                __hip_bfloat16* __restrict__ wb) {
    int t = blockIdx.x * 256 + threadIdx.x;           // 9*512*512 = 2359296
    int tap = t / (512 * 512);
    int rem = t - tap * 512 * 512;
    int o = rem >> 9, c = rem & 511;
    wb[t] = __float2bfloat16(cw[(o * 512 + c) * 9 + tap]);
}

// ---------------- xt[b][y][x][c] = bf16(x[b][c][y-2][x-2] * s[b][c]), zero pad ----
__global__ __launch_bounds__(256) void k_prep_x(const float* __restrict__ x,
                                                const float* __restrict__ s,
                                                __hip_bfloat16* __restrict__ xt) {
    __shared__ float tile[64][65];
    const int y = blockIdx.x;            // 0..67
    const int b = blockIdx.y;
    const int tid = threadIdx.x;
    const bool yin = (y >= 2 && y < 66);
    __hip_bfloat16* orow = xt + ((size_t)(b * XP + y)) * XP * 512;
    for (int c0 = 0; c0 < 512; c0 += 64) {
        if (yin) {
            for (int i = tid; i < 64 * 64; i += 256) {
                int c = i >> 6, xx = i & 63;
                tile[c][xx] = x[(((size_t)b * 512 + c0 + c) * 64 + (y - 2)) * 64 + xx]
                              * s[b * 512 + c0 + c];
            }
        }
        __syncthreads();
        for (int j = tid; j < 68 * 8; j += 256) {     // 68 x-positions, 8 c-groups of 8
            int xx = j >> 3, cg = j & 7;
            bool xin = yin && (xx >= 2 && xx < 66);
            union { ushort u[8]; float4 f4; } pk;
            #pragma unroll
            for (int k = 0; k < 8; ++k) {
                float v = xin ? tile[cg * 8 + k][xx - 2] : 0.f;
                __hip_bfloat16 h = __float2bfloat16(v);
                pk.u[k] = *reinterpret_cast<ushort*>(&h);
            }
            *reinterpret_cast<float4*>(orow + (size_t)xx * 512 + c0 + cg * 8) = pk.f4;
        }
        __syncthreads();
    }
}

// ---------------- MFMA implicit-GEMM conv ----------------
// 256 o x 128 px tile, 8 waves (512 thr), K = 9 taps x 512 c, BK=32.
// 3-buffer rotation, counted s_waitcnt vmcnt(3) (T4): prefetch distance = one
// full compute phase; loads stay in flight across raw s_barrier.
__device__ __forceinline__ void gload16u(const char* base, unsigned voff, void* l) {
    __builtin_amdgcn_global_load_lds(
        (const __attribute__((address_space(1))) unsigned*)(base + voff),
        (__attribute__((address_space(3))) unsigned*)l, 16, 0, 0);
}

__global__ __launch_bounds__(512) void k_conv_mfma(
    const __hip_bfloat16* __restrict__ wb, const __hip_bfloat16* __restrict__ xt,
    const float* __restrict__ coef, const float* __restrict__ bias,
    __hip_bfloat16* __restrict__ y1)
{
    __shared__ __hip_bfloat16 lds[3][12288];          // [buf][A(8192) | B(4096)]

    // bijective XCD swizzle (560 % 8 == 0): each XCD gets 70 consecutive flat
    // ids = 2 (b,o0) groups x 35 px tiles -> one 2.25 MB A panel L2-resident.
    int flat = blockIdx.x + 35 * (blockIdx.y + 2 * blockIdx.z);
    { int xcd = flat & 7, idx = flat >> 3; flat = xcd * 70 + idx; }
    const int pi = flat % 35;
    const int t2 = flat / 35;                         // 0..15: (oi*8 + b)
    const int b  = t2 & 7;
    const int o0 = (t2 >> 3) * 256;
    const int p0 = pi * 128;

    const int tid = threadIdx.x, wv = tid >> 6, ln = tid & 63;
    const int wm = wv >> 1, wn = wv & 1;              // 4 o-quadrants x 2 px-halves

    // ---- per-lane 32-bit staging offsets (loop-invariant), uniform bases ----
    const char* wbB = (const char*)wb;
    const char* xtB = (const char*)(xt + (size_t)b * XP * XP * 512);
    const int srow = tid >> 2, ssl = tid & 3;         // staging row 0..127, 16B slot
    const unsigned swzs = (unsigned)((ssl ^ ((srow >> 1) & 3)) << 3);
    unsigned voffA0 = ((unsigned)(o0 + srow) * 512u + swzs) * 2u;
    unsigned voffA1 = ((unsigned)(o0 + 128 + srow) * 512u + swzs) * 2u;
    unsigned voffB0;
    {
        int p = p0 + srow; if (p > NPIX - 1) p = NPIX - 1;
        int py = (int)(((unsigned)p * 63551u) >> 22); // p/66
        int px = p - py * 66;
        voffB0 = ((unsigned)(py * XP + px) * 512u + swzs) * 2u;
    }

    // ---- per-lane LDS fragment byte offsets (loop-invariant) ----
    int aoff[4], boff[4];
    #pragma unroll
    for (int f = 0; f < 4; ++f) {
        int r  = wm * 64 + f * 16 + (ln & 15);
        aoff[f] = (r * 32 + (((ln >> 4) ^ ((r >> 1) & 3)) << 3)) * 2;
        int rb = wn * 64 + f * 16 + (ln & 15);
        boff[f] = (8192 + rb * 32 + (((ln >> 4) ^ ((rb >> 1) & 3)) << 3)) * 2;
    }

    f4v acc[4][4];
    #pragma unroll
    for (int fm = 0; fm < 4; ++fm)
        #pragma unroll
        for (int fn = 0; fn < 4; ++fn) acc[fm][fn] = (f4v){0.f, 0.f, 0.f, 0.f};

    auto stage = [&](int st, int buf) {               // buf is a literal at call sites
        int tap = st >> 4;                            // uniform -> SALU
        int ki  = (tap * 11) >> 5;                    // tap/3 for tap<9
        int kj  = tap - ki * 3;
        unsigned ccb  = (unsigned)(st & 15) << 6;     // c-chunk bytes
        unsigned offA = (unsigned)tap * 524288u + ccb;            // tap*512*512*2B
        unsigned offB = (unsigned)(ki * XP + kj) * 1024u + ccb;   // (ki*XP+kj)*512*2B
        __hip_bfloat16* dst = &lds[buf][0] + wv * 512;
        gload16u(wbB, voffA0 + offA, dst);            // A rows   0..127
        gload16u(wbB, voffA1 + offA, dst + 4096);     // A rows 128..255
        gload16u(xtB, voffB0 + offB, dst + 8192);     // B rows   0..127
    };

    auto compute = [&](int buf) {                     // buf literal -> const LDS bases
        const char* base = (const char*)&lds[buf][0];
        s8v af[4], bfv[4];
        #pragma unroll
        for (int f = 0; f < 4; ++f) {
            af[f]  = *reinterpret_cast<const s8v*>(base + aoff[f]);
            bfv[f] = *reinterpret_cast<const s8v*>(base + boff[f]);
        }
        #pragma unroll
        for (int fm = 0; fm < 4; ++fm)
            #pragma unroll
            for (int fn = 0; fn < 4; ++fn)
                acc[fm][fn] = __builtin_amdgcn_mfma_f32_16x16x32_bf16(
                    af[fm], bfv[fn], acc[fm][fn], 0, 0, 0);
    };

    stage(0, 0);
    stage(1, 1);

    // main loop: steps 0..140 in groups of 3; counted vmcnt(3) keeps the
    // next step's 3 loads in flight across every barrier.
    #pragma unroll 1
    for (int st = 0; st < 141; st += 3) {
        WAITV3(); __builtin_amdgcn_s_barrier();
        compute(0); stage(st + 2, 2);
        WAITV3(); __builtin_amdgcn_s_barrier();
        compute(1); stage(st + 3, 0);
        WAITV3(); __builtin_amdgcn_s_barrier();
        compute(2); stage(st + 4, 1);
    }
    // epilogue: steps 141,142,143 (stage(143) already issued at st=139+4? no:
    // last loop iteration st=138 staged 140,141,142 -> stage 143 here).
    WAITV3(); __builtin_amdgcn_s_barrier();
    compute(0); stage(143, 2);                        // step 141 in buf0
    WAITV3(); __builtin_amdgcn_s_barrier();
    compute(1);                                       // step 142 in buf1
    WAITV0(); __builtin_amdgcn_s_barrier();
    compute(2);                                       // step 143 in buf2

    // epilogue: y1[b][o][p] bf16 = acc*coef + bias
    #pragma unroll
    for (int fm = 0; fm < 4; ++fm) {
        #pragma unroll
        for (int fn = 0; fn < 4; ++fn) {
            int p = p0 + wn * 64 + fn * 16 + (ln & 15);
            if (p < NPIX) {
                int ob = o0 + wm * 64 + fm * 16 + (ln >> 4) * 4;
                #pragma unroll
                for (int j = 0; j < 4; ++j) {
                    int o = ob + j;
                    float v = acc[fm][fn][j] * coef[b * 512 + o] + bias[o];
                    y1[((size_t)(b * 512 + o)) * NPIX + p] = __float2bfloat16(v);
                }
            }
        }
    }
}

// ---------------- fused upfirdn2(up2,pad(9,8)) -> lrelu*sqrt2,clamp -> upfirdn2(down2) ----
// 32x32 output tile. No integer div/mod; polyphase even/odd pair sharing
// (both parities share tap base (rc>>1)+5, only the coef set differs);
// float2 LDS reads in the down phases; It/zt and hu/dh share LDS regions.
__global__ __launch_bounds__(256) void k_style_fir(
    const __hip_bfloat16* __restrict__ y1, const float* __restrict__ uf,
    const float* __restrict__ df, float* __restrict__ out)
{
    __shared__ float smA[5632];          // It[42][44] then zt[74][76]
    __shared__ float smB[3200];          // hu[42][76] then dh[74][36]
    float* It = smA;                     // stride 44
    float* hu = smB;                     // stride 76
    float* zt = smA;                     // stride 76
    float* dh = smB;                     // stride 36

    const int img = blockIdx.z;          // b*COUT + o
    const int oy0 = blockIdx.y * 32;
    const int ox0 = blockIdx.x * 32;
    const int tid = threadIdx.x;
    const __hip_bfloat16* I = y1 + (size_t)img * NPIX;

    float cu[12], cd[12];
    #pragma unroll
    for (int q = 0; q < 12; ++q) { cu[q] = uf[q]; cd[q] = df[q]; }

    const int ty = tid >> 5, tx = tid & 31;   // 8 x 32
    const int ty4 = tid >> 4, tx4 = tid & 15; // 16 x 16

    // phase 0: load It[42][42] <- y1 tile rows/cols [oy0-4, oy0+37]
    #pragma unroll
    for (int k = 0; k < 6; ++k) {
        int rr = ty + 8 * k; if (rr >= 42) break;
        int gy = oy0 - 4 + rr;
        bool yin = (gy >= 0 && gy < HO_);
        #pragma unroll
        for (int j = 0; j < 2; ++j) {
            int cc = tx + 32 * j; if (cc >= 42) continue;
            int gx = ox0 - 4 + cc;
            float v = 0.f;
            if (yin && gx >= 0 && gx < HO_) v = __bfloat162float(I[gy * HO_ + gx]);
            It[rr * 44 + cc] = v;
        }
    }
    __syncthreads();

    // phase 1: horizontal up-filter, 2 outputs (parities) per 6 reads.
    // hu[m][2h+p] = 2 * sum_q uf[2q+p] * It[m][h+5-q]
    #pragma unroll
    for (int k = 0; k < 6; ++k) {
        int m = ty + 8 * k; if (m >= 42) break;
        #pragma unroll
        for (int j = 0; j < 2; ++j) {
            int h = tx + 32 * j; if (h >= 37) continue;
            float v[6];
            #pragma unroll
            for (int q = 0; q < 6; ++q) v[q] = It[m * 44 + h + 5 - q];
            float e = 0.f, o = 0.f;
            #pragma unroll
            for (int q = 0; q < 6; ++q) { e += cu[2 * q] * v[q]; o += cu[2 * q + 1] * v[q]; }
            *reinterpret_cast<float2*>(hu + m * 76 + 2 * h) = make_float2(2.f * e, 2.f * o);
        }
    }
    __syncthreads();

    // phase 2: vertical up-filter + lrelu*sqrt2 + clamp, 2 rows per 6 reads.
    #pragma unroll
    for (int k = 0; k < 5; ++k) {
        int r = ty + 8 * k; if (r >= 37) break;
        #pragma unroll
        for (int j = 0; j < 3; ++j) {
            int rx = tx + 32 * j; if (rx >= 74) continue;
            float v[6];
            #pragma unroll
            for (int q = 0; q < 6; ++q) v[q] = hu[(r + 5 - q) * 76 + rx];
            float e = 0.f, o = 0.f;
            #pragma unroll
            for (int q = 0; q < 6; ++q) { e += cu[2 * q] * v[q]; o += cu[2 * q + 1] * v[q]; }
            e *= 2.f; o *= 2.f;
            e = (e >= 0.f ? e : e * 0.2f) * 1.4142135623730951f;
            o = (o >= 0.f ? o : o * 0.2f) * 1.4142135623730951f;
            e = fminf(fmaxf(e, -256.f), 256.f);
            o = fminf(fmaxf(o, -256.f), 256.f);
            zt[(2 * r) * 76 + rx] = e;
            zt[(2 * r + 1) * 76 + rx] = o;
        }
    }
    __syncthreads();

    // phase 3: down horizontal (+decimate x), 2 adjacent outputs per 7 float2 reads.
    // dh[ry][2t+s] = sum_u zt[ry][4t+2s+u] * df[11-u]
    #pragma unroll
    for (int k = 0; k < 5; ++k) {
        int ry = ty4 + 16 * k; if (ry >= 74) break;
        const float* zr = zt + ry * 76 + 4 * tx4;
        float z[14];
        #pragma unroll
        for (int t = 0; t < 7; ++t) {
            float2 p2 = *reinterpret_cast<const float2*>(zr + 2 * t);
            z[2 * t] = p2.x; z[2 * t + 1] = p2.y;
        }
        float a0 = 0.f, a1 = 0.f;
        #pragma unroll
        for (int u = 0; u < 12; ++u) { a0 += z[u] * cd[11 - u]; a1 += z[u + 2] * cd[11 - u]; }
        *reinterpret_cast<float2*>(dh + ry * 36 + 2 * tx4) = make_float2(a0, a1);
    }
    __syncthreads();

    // phase 4: down vertical (+decimate y) + store, 2 rows per 14 reads.
    #pragma unroll
    for (int k = 0; k < 2; ++k) {
        int r2 = ty + 8 * k;                 // oy pair = (2*r2, 2*r2+1)
        float d[14];
        #pragma unroll
        for (int v = 0; v < 14; ++v) d[v] = dh[(4 * r2 + v) * 36 + tx];
        float a0 = 0.f, a1 = 0.f;
        #pragma unroll
        for (int v = 0; v < 12; ++v) { a0 += d[v] * cd[11 - v]; a1 += d[v + 2] * cd[11 - v]; }
        float* op = out + (size_t)img * 64 * 64 + (oy0 + 2 * r2) * 64 + ox0 + tx;
        op[0]  = a0;
        op[64] = a1;
    }
}

extern "C" void kernel_launch(void* const* d_in, const int* in_sizes, int n_in,
                              void* d_out, int out_size, void* d_ws, size_t ws_size,
                              hipStream_t stream) {
    const float* x    = (const float*)d_in[0];
    const float* w    = (const float*)d_in[1];
    const float* aw   = (const float*)d_in[2];
    const float* ab   = (const float*)d_in[3];
    const float* cw   = (const float*)d_in[4];
    const float* bias = (const float*)d_in[5];
    const float* uf   = (const float*)d_in[6];
    const float* df   = (const float*)d_in[7];
    const float* ema  = (const float*)d_in[8];
    float* out = (float*)d_out;

    float* ws   = (float*)d_ws;
    float* s_   = ws;                                   // 4096
    float* coef = ws + 4096;                            // 4096
    float* r_   = ws + 8192;                            // 262144
    // bf16 regions (sizes in float-slots): y1 8,921,088 | xt 9,469,952 | wb 1,179,648
    __hip_bfloat16* y1 = (__hip_bfloat16*)(ws + 270336);
    __hip_bfloat16* xt = (__hip_bfloat16*)(ws + 270336 + 8921088);
    __hip_bfloat16* wb = (__hip_bfloat16*)(ws + 270336 + 8921088 + 9469952);

    k_style_s   <<<16,   256, 0, stream>>>(w, aw, ab, s_);
    k_style_r   <<<1024, 256, 0, stream>>>(cw, r_);
    k_style_coef<<<16,   256, 0, stream>>>(s_, r_, ema, coef);
    k_prep_w    <<<9216, 256, 0, stream>>>(cw, wb);
    k_prep_x    <<<dim3(68, 8), 256, 0, stream>>>(x, s_, xt);
    k_conv_mfma <<<dim3(35, 2, 8), 512, 0, stream>>>(wb, xt, coef, bias, y1);
    k_style_fir <<<dim3(2, 2, 4096), 256, 0, stream>>>(y1, uf, df, out);
}